// Round 1
// baseline (288.824 us; speedup 1.0000x reference)
//
#include <hip/hip_runtime.h>

#define B_    32
#define S_    4096
#define CIN_  7
#define NF_   35      // 5 * CIN
#define D_    512
#define WIN_  24
#define K3_   105     // NF * 3 (GEMM K)
#define P_    120     // LDS A row stride in bf16 elems (mult of 8, not pow2)
#define QN_   66      // tap positions per s-tile: s0-1 .. s0+64

typedef __attribute__((ext_vector_type(8))) short short8;   // 8 x bf16 (4 VGPR)
typedef __attribute__((ext_vector_type(4))) float float4_;  // MFMA C/D

__device__ __forceinline__ unsigned short f2bf(float f) {
    unsigned int u = __builtin_bit_cast(unsigned int, f);
    u += 0x7FFFu + ((u >> 16) & 1u);          // RNE to bf16
    return (unsigned short)(u >> 16);
}

// ---------------------------------------------------------------------------
// Pack W (512, 35, 3) fp32 -> bf16 fragments, fragment-linear:
//   slot(nsub 0..31, kstep 0..3, lane 0..63) holds 8 bf16:
//     Wt[d = nsub*16 + (lane&15)][k = kstep*32 + (lane>>4)*8 + j],  j=0..7
//     (zero-padded for k >= 105)
// This layout serves as the MFMA **A-operand** fragment (row = lane&15,
// k = (lane>>4)*8+j) — identical bytes to the previous B-operand use, since
// A- and B-fragment lane layouts are symmetric for 16x16x32.
// ---------------------------------------------------------------------------
__global__ __launch_bounds__(256) void pack_w_kernel(
    const float* __restrict__ W, short* __restrict__ Bf)
{
    const int slot = blockIdx.x * 256 + threadIdx.x;   // 0..8191
    if (slot >= 32 * 4 * 64) return;
    const int l     = slot & 63;
    const int kstep = (slot >> 6) & 3;
    const int nsub  = slot >> 8;
    const int d  = nsub * 16 + (l & 15);
    const int kb = kstep * 32 + (l >> 4) * 8;

    short8 v;
    #pragma unroll
    for (int j = 0; j < 8; ++j) {
        const int kappa = kb + j;
        v[j] = (kappa < K3_) ? (short)f2bf(W[(size_t)d * K3_ + kappa]) : (short)0;
    }
    *(short8*)(Bf + (size_t)slot * 8) = v;
}

// ---------------------------------------------------------------------------
// Fused kernel: rolling stats -> bf16 A-tile in LDS -> MFMA GEMM -> out.
// Block: 512 threads = 8 waves; blockIdx = (s-tile of 64, b).
// Wave w covers d = w*64 .. w*64+63 as a 4x4 grid of 16x16x32 bf16 MFMAs.
//
// OPERAND SWAP vs previous version: mfma(Wfrag, Ffrag) so that
//   D[row = d' = quad*4+reg][col = s' = lane&15]
// -> each thread's 4 acc regs are 4 CONSECUTIVE d columns of ONE output row
// -> epilogue is 16 global_store_dwordx4 per thread instead of 64 dwords.
// ---------------------------------------------------------------------------
template <bool USE_WS>
__global__ __launch_bounds__(512, 4) void fused_mfma_kernel(
    const float* __restrict__ x, const float* __restrict__ W,
    const short* __restrict__ Bf, const float* __restrict__ bias,
    float* __restrict__ out)
{
    __shared__ short sA[64 * P_];            // F[s'=0..63][kappa], bf16 bits

    const int tid = threadIdx.x;
    const int s0  = blockIdx.x * 64;
    const int b   = blockIdx.y;

    // ---- Phase 1: stats for taps q=0..65 (s = s0-1+q circular), to LDS ----
    if (tid < QN_ * CIN_) {
        const int q = tid / CIN_;
        const int f = tid - q * CIN_;
        int p = s0 - 1 + q;
        const int sm = p < 0 ? p + S_ : (p >= S_ ? p - S_ : p);
        const float* xb = x + (size_t)b * S_ * CIN_ + f;

        float v[WIN_];
        #pragma unroll
        for (int j = 0; j < WIN_; ++j) {
            int sc = sm - (WIN_ - 1) + j;    // front-clamped window
            sc = sc < 0 ? 0 : sc;
            v[j] = xb[(size_t)sc * CIN_];
        }
        float sum = 0.f, mx = v[0], mn = v[0];
        #pragma unroll
        for (int j = 0; j < WIN_; ++j) {
            sum += v[j];
            mx = fmaxf(mx, v[j]);
            mn = fminf(mn, v[j]);
        }
        const float mean = sum * (1.0f / WIN_);
        float var = 0.f;
        #pragma unroll
        for (int j = 0; j < WIN_; ++j) {
            const float dv = v[j] - mean;
            var = fmaf(dv, dv, var);
        }
        const float sd = sqrtf(var * (1.0f / (WIN_ - 1)) + 1e-12f);

        const float vals[5] = { v[WIN_ - 1], mean, mx, mn, sd };
        // A[m][kappa=i*3+k] = tap[i][q] with m = q - k
        #pragma unroll
        for (int k = 0; k < 3; ++k) {
            const int m = q - k;
            if (m >= 0 && m < 64) {
                #pragma unroll
                for (int g = 0; g < 5; ++g) {
                    const int i = f + g * CIN_;
                    sA[m * P_ + i * 3 + k] = (short)f2bf(vals[g]);
                }
            }
        }
    }
    // zero the K padding (kappa = 105..119); B pad is zero too, but LDS
    // garbage could be NaN-patterned and NaN*0 = NaN.
    for (int t = tid; t < 64 * (P_ - K3_); t += 512) {
        const int m = t / (P_ - K3_);
        const int c = K3_ + (t - m * (P_ - K3_));
        sA[m * P_ + c] = 0;
    }
    __syncthreads();

    // ---- Phase 2: MFMA GEMM (W as A-operand, F as B-operand) ----
    const int w  = tid >> 6;          // wave id 0..7 -> d base = w*64
    const int l  = tid & 63;
    const int lr = l & 15;            // 16-index: F row (s') / W row (d')
    const int lq = l >> 4;            // quad

    float4_ acc[4][4];                // [m = s-subtile][n = d-subtile]
    #pragma unroll
    for (int n = 0; n < 4; ++n) {
        // bias for d = w*64 + n*16 + lq*4 + r, r=0..3 -> one float4 load
        const float4_ bv = *(const float4_*)(bias + w * 64 + n * 16 + lq * 4);
        #pragma unroll
        for (int m = 0; m < 4; ++m) acc[m][n] = bv;
    }

    #pragma unroll
    for (int ks = 0; ks < 4; ++ks) {
        // F fragments (B-operand): B[k][s'] -> lane holds s'=lr, k=ks*32+lq*8+j
        short8 ff[4];
        #pragma unroll
        for (int m = 0; m < 4; ++m)
            ff[m] = *(const short8*)&sA[(m * 16 + lr) * P_ + ks * 32 + lq * 8];

        // W fragments (A-operand): A[d'][k] -> lane holds d'=lr, k=ks*32+lq*8+j
        short8 wf[4];
        #pragma unroll
        for (int n = 0; n < 4; ++n) {
            if (USE_WS) {
                const int nsub = w * 4 + n;
                wf[n] = *(const short8*)(Bf + ((size_t)(nsub * 4 + ks) * 64 + l) * 8);
            } else {
                const int d  = w * 64 + n * 16 + lr;
                const int kb = ks * 32 + lq * 8;
                short8 t8;
                #pragma unroll
                for (int j = 0; j < 8; ++j)
                    t8[j] = (kb + j < K3_) ? (short)f2bf(W[(size_t)d * K3_ + kb + j])
                                           : (short)0;
                wf[n] = t8;
            }
        }

        #pragma unroll
        for (int m = 0; m < 4; ++m)
            #pragma unroll
            for (int n = 0; n < 4; ++n)
                acc[m][n] = __builtin_amdgcn_mfma_f32_16x16x32_bf16(
                    wf[n], ff[m], acc[m][n], 0, 0, 0);
    }

    // ---- Epilogue: D row = d' = lq*4+r, col = s' = lr ----
    // Thread owns 4 consecutive d at one s -> float4 stores.
    #pragma unroll
    for (int m = 0; m < 4; ++m) {
        float* ob = out + ((size_t)(b * S_ + s0 + m * 16 + lr)) * D_
                        + w * 64 + lq * 4;
        #pragma unroll
        for (int n = 0; n < 4; ++n)
            *(float4_*)(ob + n * 16) = acc[m][n];
    }
}

// ---------------------------------------------------------------------------
extern "C" void kernel_launch(void* const* d_in, const int* in_sizes, int n_in,
                              void* d_out, int out_size, void* d_ws, size_t ws_size,
                              hipStream_t stream) {
    const float* x      = (const float*)d_in[0];   // (32, 4096, 7)
    // d_in[1] = x_mark: unused by the reference
    const float* W_conv = (const float*)d_in[2];   // (512, 35, 3)
    const float* b_conv = (const float*)d_in[3];   // (512,)
    float* out = (float*)d_out;                    // (32, 4096, 512)

    const size_t bf_bytes = (size_t)32 * 4 * 64 * 8 * sizeof(short);  // 128 KiB

    if (ws_size >= bf_bytes) {
        short* Bf = (short*)d_ws;
        pack_w_kernel<<<dim3(32), dim3(256), 0, stream>>>(W_conv, Bf);
        fused_mfma_kernel<true><<<dim3(S_ / 64, B_), dim3(512), 0, stream>>>(
            x, W_conv, Bf, b_conv, out);
    } else {
        fused_mfma_kernel<false><<<dim3(S_ / 64, B_), dim3(512), 0, stream>>>(
            x, W_conv, nullptr, b_conv, out);
    }
}